// Round 1
// 62.731 us; speedup vs baseline: 1.0046x; 1.0046x over previous
//
#include <hip/hip_runtime.h>

// Problem constants (match reference): R rules, A antecedents, B samples.
#define RR 32
#define AA 16
#define SPLIT 4                 // rule-quarters, one per wave of the block
#define RPW (RR / SPLIT)        // 8 rules per wave
#define BLOCK 256               // 4 waves
#define SPB 64                  // samples per block (one per lane)

// Single fused kernel. Each block rebuilds the 32-rule coefficient table in
// LDS (512 entries over 256 threads — 2 per thread, W/C are L2-hot), then the
// 4 waves each evaluate an 8-rule quarter for the block's 64 samples.
// Layout in Pl, per rule r (64-float stride):
//   Pl[r*64 +  0 .. 15] = a_k  = -0.5/sigma^2 * log2(e)
//   Pl[r*64 + 16 .. 31] = b_k  =  c/sigma^2   * log2(e)
//   Pl[r*64 + 32 .. 47] = Cw_k =  C[r][1+k]
//   Pl[r*64 + 48]       = bias =  C[r][0]
//   Pl[r*64 + 49]       = K_r  =  sum_k(-0.5 c^2/sigma^2) * log2(e)
__global__ __launch_bounds__(BLOCK, 4) void tsk_fused(
    const float* __restrict__ x,   // [B, A] row-major
    const float* __restrict__ W,   // FRB_W, 2*R*A floats
    const float* __restrict__ C,   // [R, A+1] row-major
    float* __restrict__ out,       // [B]
    int B)
{
    __shared__ float Pl[RR * 64];        // 8 KB coefficient table
    __shared__ float cpart[RR * AA];     // 2 KB scratch for K_r reduction
    __shared__ float pnum[SPLIT][SPB];
    __shared__ float pden[SPLIT][SPB];

    const float LOG2E = 1.4426950408889634f;
    const int tid  = threadIdx.x;
    const int lane = tid & 63;
    // Force wave-uniformity into an SGPR so loop bases are provably scalar.
    const int wv = __builtin_amdgcn_readfirstlane(tid >> 6);  // 0..3

    // ---- issue the sample loads FIRST: global latency overlaps precompute ----
    int s = blockIdx.x * SPB + lane;
    int sl = s < B ? s : B - 1;          // clamp (no early return)
    const float4* xr = (const float4*)(x + (size_t)sl * AA);
    float4 v0 = xr[0], v1 = xr[1], v2 = xr[2], v3 = xr[3];

    // ---- per-block coefficient precompute (replaces the old grid-1 kernel) ----
    #pragma unroll
    for (int i = tid; i < RR * AA; i += BLOCK) {
        int r = i >> 4, k = i & 15;
        // Faithful to reference indexing: sigma = W[A*r+k], center = W[A*r+k+1]
        float sig = W[i];
        float c   = W[i + 1];
        float inv2 = 1.0f / (sig * sig);
        Pl[r * 64 + k]      = -0.5f * inv2 * LOG2E;        // a
        Pl[r * 64 + 16 + k] = c * inv2 * LOG2E;            // b
        Pl[r * 64 + 32 + k] = C[r * (AA + 1) + 1 + k];     // consequent weight
        cpart[i]            = -0.5f * c * c * inv2 * LOG2E;
    }
    __syncthreads();
    if (tid < RR) {
        float ssum = 0.0f;
        #pragma unroll
        for (int k = 0; k < AA; ++k) ssum += cpart[tid * AA + k];
        Pl[tid * 64 + 49] = ssum;                          // K_r
        Pl[tid * 64 + 48] = C[tid * (AA + 1)];             // bias
    }
    __syncthreads();

    float xv[AA] = { v0.x, v0.y, v0.z, v0.w,
                     v1.x, v1.y, v1.z, v1.w,
                     v2.x, v2.y, v2.z, v2.w,
                     v3.x, v3.y, v3.z, v3.w };
    float x2[AA];
    #pragma unroll
    for (int k = 0; k < AA; ++k) x2[k] = xv[k] * xv[k];

    float num = 0.0f, den = 0.0f;
    const float* pw = Pl + wv * RPW * 64;  // wave-uniform LDS base
    #pragma unroll 2
    for (int r = 0; r < RPW; ++r) {
        const float* p = pw + r * 64;
        float ea = 0.0f, eb = 0.0f;
        float ch = p[48];
        #pragma unroll
        for (int k = 0; k < AA; ++k) {
            ea = fmaf(p[k],      x2[k], ea);   // sum a*x^2 (uniform LDS bcast)
            eb = fmaf(p[16 + k], xv[k], eb);   // sum b*x
            ch = fmaf(p[32 + k], xv[k], ch);   // consequent dot
        }
        float w = __builtin_amdgcn_exp2f(ea + eb + p[49]);  // log2e folded in
        num = fmaf(w, ch, num);
        den += w;
    }

    pnum[wv][lane] = num;
    pden[wv][lane] = den;
    __syncthreads();

    if (tid < SPB) {
        float n = pnum[0][tid] + pnum[1][tid] + pnum[2][tid] + pnum[3][tid];
        float d = pden[0][tid] + pden[1][tid] + pden[2][tid] + pden[3][tid];
        int so = blockIdx.x * SPB + tid;
        if (so < B) out[so] = n * __builtin_amdgcn_rcpf(d);
    }
}

extern "C" void kernel_launch(void* const* d_in, const int* in_sizes, int n_in,
                              void* d_out, int out_size, void* d_ws, size_t ws_size,
                              hipStream_t stream) {
    const float* x = (const float*)d_in[0];   // input_data [B, A]
    const float* W = (const float*)d_in[1];   // FRB_W [2*R*A]
    const float* C = (const float*)d_in[2];   // C [R, A+1]
    float* out = (float*)d_out;
    int B = in_sizes[0] / AA;
    (void)d_ws; (void)ws_size;                // workspace no longer used

    tsk_fused<<<dim3((B + SPB - 1) / SPB), dim3(BLOCK), 0, stream>>>(x, W, C, out, B);
}